// Round 7
// baseline (543.001 us; speedup 1.0000x reference)
//
#include <hip/hip_runtime.h>

typedef unsigned short u16;
typedef unsigned int u32;
typedef __attribute__((ext_vector_type(8))) short bf16x8;
typedef __attribute__((ext_vector_type(4))) float f32x4;

__device__ __forceinline__ u16 f2bf(float f) {
    u32 u = __float_as_uint(f);
    u += 0x7fffu + ((u >> 16) & 1u);   // RNE
    return (u16)(u >> 16);
}

__device__ __forceinline__ void llds16(void* l, const void* g) {
    __builtin_amdgcn_global_load_lds(
        (const __attribute__((address_space(1))) u32*)g,
        (__attribute__((address_space(3))) u32*)l, 16, 0, 0);
}

// ---- prep (single dispatch): x NCHW f32 -> NHWC bf16, w -> [p][co][ci] bf16,
//      BN fold (s=g*rsqrt(v+eps), t=b-m*s), 2KB zero page ---------------------
__global__ void prep(const float* __restrict__ x, u16* __restrict__ xt,
                     const float* __restrict__ w1, const float* __restrict__ w2,
                     u16* __restrict__ W1t, u16* __restrict__ W2t,
                     const float* __restrict__ g1, const float* __restrict__ b1,
                     const float* __restrict__ rm1, const float* __restrict__ rv1,
                     const float* __restrict__ g2, const float* __restrict__ b2,
                     const float* __restrict__ rm2, const float* __restrict__ rv2,
                     float* __restrict__ sc, u32* __restrict__ zp) {
    int t = threadIdx.x;
    int b = blockIdx.x;
    if (b < 16384) {
        // x transpose: 64 n * 32 h * 8 cb blocks; 32c x 32w tile via LDS
        __shared__ float xl[32 * 33];
        int n = b >> 8, rem = b & 255;
        int h = rem >> 3, c0 = (rem & 7) << 5;
        int cl = t >> 5, w = t & 31;
#pragma unroll
        for (int i = 0; i < 4; ++i) {
            int c = c0 + i * 8 + cl;
            xl[(i * 8 + cl) * 33 + w] = x[(n * 256 + c) * 1024 + h * 32 + w];
        }
        __syncthreads();
        int wo = t >> 3, k = t & 7;
        ushort4 o;
        o.x = f2bf(xl[(k * 4 + 0) * 33 + wo]);
        o.y = f2bf(xl[(k * 4 + 1) * 33 + wo]);
        o.z = f2bf(xl[(k * 4 + 2) * 33 + wo]);
        o.w = f2bf(xl[(k * 4 + 3) * 33 + wo]);
        *(ushort4*)&xt[((n * 32 + h) * 32 + wo) * 256 + c0 + k * 4] = o;
    } else {
        int bb = b - 16384;                     // 0..511
        int idx = (bb & 255) * 256 + t;         // (co,ci) pair
        const float* src = (bb >> 8) ? w2 : w1;
        u16* dst = (bb >> 8) ? W2t : W1t;
        const float* s = src + idx * 9;
        int co = idx >> 8, ci = idx & 255;
#pragma unroll
        for (int p = 0; p < 9; ++p)
            dst[p * 65536 + co * 256 + ci] = f2bf(s[p]);
        if (bb == 0) {
            float s1 = g1[t] * rsqrtf(rv1[t] + 1e-5f);
            sc[t]       = s1;
            sc[256 + t] = b1[t] - rm1[t] * s1;
            float s2 = g2[t] * rsqrtf(rv2[t] + 1e-5f);
            sc[512 + t] = s2;
            sc[768 + t] = b2[t] - rm2[t] * s2;
            zp[t] = 0u;            // 2KB zero page (512 u32)
            zp[t + 256] = 0u;
        }
    }
}

// ---- main: fused conv3x3 + BN (+skip) + ReLU via MFMA implicit GEMM --------
// Block: 64 c_out x (8h x 32w), 4 waves, wave = 64co x 64sp = 4x4 16x16x32.
// KEY CHANGE vs R6: LDS shaved 59392 -> 51200 B => 3 blocks/CU (12 waves/CU,
// 3 waves/SIMD instead of 2). Six rounds showed co-resident wave count is the
// only lever that moved perf (m114 implicit overlap); this pushes it UP.
// How: taps p=7,8 of A live in per-wave REGISTERS (loaded direct from global,
// L2-hit: 4 co-tiles/XCD re-hit the same W lines), ldsA holds only p=0..6.
// To keep both reg-taps single-buffered (rule #20), compute order is
// kw=1 (p=1,4,7), kw=2 (p=2,5,8), tail kw=0 (p=0,3,6 all-LDS): reg frags are
// consumed BEFORE the mid-step staging point overwrites them.
// Staging-under-tail (R6): next step's llds16 + reg loads issue after the mid
// barrier, shadowed by the 48 tail MFMAs; step-top vmcnt(0) is then ~free.
// XCD swizzle: bid%8 pins the XCD slot.
__global__ __launch_bounds__(256, 3) void conv_mfma(
    const u16* __restrict__ Xt,    // NHWC bf16 input
    const u16* __restrict__ Wt,    // [9][256][256] bf16
    const float* __restrict__ sv,  // scale[256]
    const float* __restrict__ tv,  // shift[256]
    const float* __restrict__ skip,// NCHW f32 (stage2) or null
    u16* __restrict__ ybf,         // NHWC bf16 out (stage1)
    float* __restrict__ yf,        // NCHW f32 out (stage2)
    const u16* __restrict__ zp, int stage)
{
    __shared__ alignas(16) u16 ldsA[7 * 4 * 64 * 8];   // 28 chunks = 28672 B
    __shared__ alignas(16) u16 ldsB[22 * 64 * 8];      // 22 chunks = 22528 B

    int t = threadIdx.x;
    int wv = t >> 6, lane = t & 63;
    int q = lane >> 4, n16 = lane & 15;

    // XCD-aware decode: k = bid&7 (XCD slot), co varies within a 32-bid window
    int bid = blockIdx.x;
    int co_t = (bid >> 3) & 3;
    int sp   = ((bid >> 5) << 3) | (bid & 7);   // 0..255 spatial tile
    int h_t  = sp & 3, nb = sp >> 2;
    int co0 = co_t << 6, h0 = h_t << 3;

    // ---- staging source pointers (kc added in-loop) ----
    // A (LDS): 7 chunks/wave, g = wv*7+i -> (p = g>>2, mt = g&3), p in 0..6;
    // lane fetches Wt[p][co0 + mt*16 + n16][q*8 + kc]
    const u16* aSrc[7];
#pragma unroll
    for (int i = 0; i < 7; ++i) {
        int g = wv * 7 + i;
        int p = g >> 2, mt = g & 3;
        aSrc[i] = Wt + (p << 16) + ((co0 + (mt << 4) + n16) << 8) + (q << 3);
    }
    // A (regs): taps p=7,8, per-wave fragment sources (same lane mapping)
    const u16* a7Src[4];
    const u16* a8Src[4];
#pragma unroll
    for (int mt = 0; mt < 4; ++mt) {
        a7Src[mt] = Wt + (7 << 16) + ((co0 + (mt << 4) + n16) << 8) + (q << 3);
        a8Src[mt] = Wt + (8 << 16) + ((co0 + (mt << 4) + n16) << 8) + (q << 3);
    }
    // B: 22 chunks total; chunk g2 = wv*6+j (skip g2>=22); slot s = g2*64+lane;
    // s -> hi = s/136, wp = (s%136)>>2, qq = s&3; halo/OOB -> zero page.
    const u16* bSrc[6];
#pragma unroll
    for (int j = 0; j < 6; ++j) {
        int g2 = wv * 6 + j;
        if (g2 < 22) {
            int s = g2 * 64 + lane;
            int hi = s / 136, rem = s - hi * 136;
            int wp = rem >> 2, qq = rem & 3;
            int hin = h0 - 1 + hi;
            bool v = (wp >= 1) && (wp <= 32) && (hin >= 0) && (hin < 32);
            bSrc[j] = v ? (Xt + (((nb << 5) + hin) * 32 + (wp - 1)) * 256 + (qq << 3))
                        : (zp + lane * 8);      // zp is 2KB: +kc stays in-bounds
        } else {
            bSrc[j] = zp + lane * 8;
        }
    }

    f32x4 acc[4][4] = {};
    bf16x8 Ap7[4], Ap8[4];          // reg-resident taps p=7, p=8

    // prologue: stage kc=0
#pragma unroll
    for (int i = 0; i < 7; ++i)
        llds16(&ldsA[(wv * 7 + i) << 9], aSrc[i]);
#pragma unroll
    for (int j = 0; j < 6; ++j) {
        int g2 = wv * 6 + j;
        if (g2 < 22) llds16(&ldsB[g2 << 9], bSrc[j]);
    }
#pragma unroll
    for (int mt = 0; mt < 4; ++mt) {
        Ap7[mt] = *(const bf16x8*)(a7Src[mt]);
        Ap8[mt] = *(const bf16x8*)(a8Src[mt]);
    }

    for (int kt = 0; kt < 8; ++kt) {
        // staging for this step was issued ~2K cyc ago (under prev tail MFMAs)
        asm volatile("s_waitcnt vmcnt(0)" ::: "memory");
        __builtin_amdgcn_s_barrier();

        // ---- kw = 1,2: interleaved read/MFMA; p=7 (kw1,kh2) and p=8
        //      (kw2,kh2) come from registers ----
#pragma unroll
        for (int kw = 1; kw <= 2; ++kw) {
            bf16x8 bFr[4][2];
#pragma unroll
            for (int r = 0; r < 4; ++r)
#pragma unroll
                for (int half = 0; half < 2; ++half) {
                    int hi = (wv << 1) + r;
                    int wp = (half << 4) + n16 + kw;
                    bFr[r][half] = *(const bf16x8*)
                        &ldsB[(hi * 136 + (wp << 2) + q) << 3];
                }
            __builtin_amdgcn_s_setprio(1);
#pragma unroll
            for (int kh = 0; kh < 3; ++kh) {
                const int p = kh * 3 + kw;
                bf16x8 aF[4];
#pragma unroll
                for (int mt = 0; mt < 4; ++mt)
                    aF[mt] = (p <= 6)
                        ? *(const bf16x8*)&ldsA[((p << 8) + (mt << 6) + lane) << 3]
                        : ((p == 7) ? Ap7[mt] : Ap8[mt]);
#pragma unroll
                for (int mt = 0; mt < 4; ++mt)
#pragma unroll
                    for (int nt = 0; nt < 4; ++nt)
                        acc[mt][nt] = __builtin_amdgcn_mfma_f32_16x16x32_bf16(
                            aF[mt], bFr[(nt >> 1) + kh][nt & 1], acc[mt][nt], 0, 0, 0);
            }
            __builtin_amdgcn_s_setprio(0);
        }

        // ---- tail group kw = 0 (p=0,3,6 all LDS): hoist reads, mid barrier,
        //      stage next step under the tail MFMAs ----
        bf16x8 bF2[4][2];
        bf16x8 aF2[3][4];
#pragma unroll
        for (int r = 0; r < 4; ++r)
#pragma unroll
            for (int half = 0; half < 2; ++half) {
                int hi = (wv << 1) + r;
                int wp = (half << 4) + n16;       // kw = 0
                bF2[r][half] = *(const bf16x8*)
                    &ldsB[(hi * 136 + (wp << 2) + q) << 3];
            }
#pragma unroll
        for (int kh = 0; kh < 3; ++kh) {
            const int p = kh * 3;                 // 0, 3, 6
#pragma unroll
            for (int mt = 0; mt < 4; ++mt)
                aF2[kh][mt] = *(const bf16x8*)&ldsA[((p << 8) + (mt << 6) + lane) << 3];
        }
        // my reads must have LANDED before anyone overwrites the buffers
        asm volatile("s_waitcnt lgkmcnt(0)" ::: "memory");
        __builtin_amdgcn_sched_barrier(0);
        __builtin_amdgcn_s_barrier();     // all waves done reading this step

        // issue next step's staging NOW (overwrite safe; reg taps for this
        // step were consumed in the kw=1,2 groups above); the 48 tail MFMAs
        // below shadow the L2 latency + BW
        if (kt < 7) {
            int kc = (kt + 1) << 5;
#pragma unroll
            for (int i = 0; i < 7; ++i)
                llds16(&ldsA[(wv * 7 + i) << 9], aSrc[i] + kc);
#pragma unroll
            for (int j = 0; j < 6; ++j) {
                int g2 = wv * 6 + j;
                if (g2 < 22) llds16(&ldsB[g2 << 9], bSrc[j] + kc);
            }
#pragma unroll
            for (int mt = 0; mt < 4; ++mt) {
                Ap7[mt] = *(const bf16x8*)(a7Src[mt] + kc);
                Ap8[mt] = *(const bf16x8*)(a8Src[mt] + kc);
            }
        }
        __builtin_amdgcn_sched_barrier(0); // keep staging issue before MFMAs

        __builtin_amdgcn_s_setprio(1);
#pragma unroll
        for (int kh = 0; kh < 3; ++kh)
#pragma unroll
            for (int mt = 0; mt < 4; ++mt)
#pragma unroll
                for (int nt = 0; nt < 4; ++nt)
                    acc[mt][nt] = __builtin_amdgcn_mfma_f32_16x16x32_bf16(
                        aF2[kh][mt], bF2[(nt >> 1) + kh][nt & 1], acc[mt][nt], 0, 0, 0);
        __builtin_amdgcn_s_setprio(0);
    }

    // epilogue: C/D layout col=lane&15 (spatial w), row=q*4+reg (c_out)
    if (stage == 1) {
#pragma unroll
        for (int mt = 0; mt < 4; ++mt) {
            int cb = co0 + (mt << 4) + (q << 2);
            f32x4 ss = *(const f32x4*)&sv[cb];
            f32x4 tt = *(const f32x4*)&tv[cb];
#pragma unroll
            for (int nt = 0; nt < 4; ++nt) {
                int h = h0 + (wv << 1) + (nt >> 1), w = ((nt & 1) << 4) + n16;
                ushort4 o;
                o.x = f2bf(fmaxf(acc[mt][nt][0] * ss[0] + tt[0], 0.f));
                o.y = f2bf(fmaxf(acc[mt][nt][1] * ss[1] + tt[1], 0.f));
                o.z = f2bf(fmaxf(acc[mt][nt][2] * ss[2] + tt[2], 0.f));
                o.w = f2bf(fmaxf(acc[mt][nt][3] * ss[3] + tt[3], 0.f));
                *(ushort4*)&ybf[(((nb << 5) + h) * 32 + w) * 256 + cb] = o;
            }
        }
    } else {
#pragma unroll
        for (int mt = 0; mt < 4; ++mt) {
            int cb = co0 + (mt << 4) + (q << 2);
            f32x4 ss = *(const f32x4*)&sv[cb];
            f32x4 tt = *(const f32x4*)&tv[cb];
#pragma unroll
            for (int nt = 0; nt < 4; ++nt) {
                int h = h0 + (wv << 1) + (nt >> 1), w = ((nt & 1) << 4) + n16;
#pragma unroll
                for (int j = 0; j < 4; ++j) {
                    int idx = (((nb << 8) + cb + j) << 10) + (h << 5) + w;
                    yf[idx] = fmaxf(acc[mt][nt][j] * ss[j] + tt[j] + skip[idx], 0.f);
                }
            }
        }
    }
}

extern "C" void kernel_launch(void* const* d_in, const int* in_sizes, int n_in,
                              void* d_out, int out_size, void* d_ws, size_t ws_size,
                              hipStream_t stream) {
    const float* x   = (const float*)d_in[0];
    const float* w1  = (const float*)d_in[1];
    const float* g1  = (const float*)d_in[2];
    const float* b1  = (const float*)d_in[3];
    const float* rm1 = (const float*)d_in[4];
    const float* rv1 = (const float*)d_in[5];
    const float* w2  = (const float*)d_in[6];
    const float* g2  = (const float*)d_in[7];
    const float* b2  = (const float*)d_in[8];
    const float* rm2 = (const float*)d_in[9];
    const float* rv2 = (const float*)d_in[10];

    char* ws = (char*)d_ws;
    u16*  XT  = (u16*)(ws);                    // 32 MB NHWC bf16 x
    u16*  H1  = (u16*)(ws + 33554432);         // 32 MB NHWC bf16 intermediate
    u16*  W1t = (u16*)(ws + 67108864);         // 1.18 MB
    u16*  W2t = (u16*)(ws + 68288512);         // 1.18 MB
    float* sc = (float*)(ws + 69468160);       // s1|t1|s2|t2, 256 f32 each
    u32*  zpg = (u32*)(ws + 69472256);         // 2 KB zeros
    if (ws_size < 69474304) return;            // workspace too small — bail

    prep<<<16896, 256, 0, stream>>>(x, XT, w1, w2, W1t, W2t,
                                    g1, b1, rm1, rv1, g2, b2, rm2, rv2,
                                    sc, zpg);

    conv_mfma<<<1024, 256, 0, stream>>>(XT, W1t, sc, sc + 256, nullptr,
                                        H1, nullptr, (const u16*)zpg, 1);
    conv_mfma<<<1024, 256, 0, stream>>>(H1, W2t, sc + 512, sc + 768, x,
                                        nullptr, (float*)d_out, (const u16*)zpg, 2);
}

// Round 8
// 322.294 us; speedup vs baseline: 1.6848x; 1.6848x over previous
//
#include <hip/hip_runtime.h>

typedef unsigned short u16;
typedef unsigned int u32;
typedef __attribute__((ext_vector_type(8))) short bf16x8;
typedef __attribute__((ext_vector_type(4))) float f32x4;

__device__ __forceinline__ u16 f2bf(float f) {
    u32 u = __float_as_uint(f);
    u += 0x7fffu + ((u >> 16) & 1u);   // RNE
    return (u16)(u >> 16);
}

__device__ __forceinline__ void llds16(void* l, const void* g) {
    __builtin_amdgcn_global_load_lds(
        (const __attribute__((address_space(1))) u32*)g,
        (__attribute__((address_space(3))) u32*)l, 16, 0, 0);
}

// ---- prep (single dispatch): x NCHW f32 -> NHWC bf16, w -> [p][co][ci] bf16,
//      BN fold (s=g*rsqrt(v+eps), t=b-m*s), 2KB zero page ---------------------
__global__ void prep(const float* __restrict__ x, u16* __restrict__ xt,
                     const float* __restrict__ w1, const float* __restrict__ w2,
                     u16* __restrict__ W1t, u16* __restrict__ W2t,
                     const float* __restrict__ g1, const float* __restrict__ b1,
                     const float* __restrict__ rm1, const float* __restrict__ rv1,
                     const float* __restrict__ g2, const float* __restrict__ b2,
                     const float* __restrict__ rm2, const float* __restrict__ rv2,
                     float* __restrict__ sc, u32* __restrict__ zp) {
    int t = threadIdx.x;
    int b = blockIdx.x;
    if (b < 16384) {
        // x transpose: 64 n * 32 h * 8 cb blocks; 32c x 32w tile via LDS
        __shared__ float xl[32 * 33];
        int n = b >> 8, rem = b & 255;
        int h = rem >> 3, c0 = (rem & 7) << 5;
        int cl = t >> 5, w = t & 31;
#pragma unroll
        for (int i = 0; i < 4; ++i) {
            int c = c0 + i * 8 + cl;
            xl[(i * 8 + cl) * 33 + w] = x[(n * 256 + c) * 1024 + h * 32 + w];
        }
        __syncthreads();
        int wo = t >> 3, k = t & 7;
        ushort4 o;
        o.x = f2bf(xl[(k * 4 + 0) * 33 + wo]);
        o.y = f2bf(xl[(k * 4 + 1) * 33 + wo]);
        o.z = f2bf(xl[(k * 4 + 2) * 33 + wo]);
        o.w = f2bf(xl[(k * 4 + 3) * 33 + wo]);
        *(ushort4*)&xt[((n * 32 + h) * 32 + wo) * 256 + c0 + k * 4] = o;
    } else {
        int bb = b - 16384;                     // 0..511
        int idx = (bb & 255) * 256 + t;         // (co,ci) pair
        const float* src = (bb >> 8) ? w2 : w1;
        u16* dst = (bb >> 8) ? W2t : W1t;
        const float* s = src + idx * 9;
        int co = idx >> 8, ci = idx & 255;
#pragma unroll
        for (int p = 0; p < 9; ++p)
            dst[p * 65536 + co * 256 + ci] = f2bf(s[p]);
        if (bb == 0) {
            float s1 = g1[t] * rsqrtf(rv1[t] + 1e-5f);
            sc[t]       = s1;
            sc[256 + t] = b1[t] - rm1[t] * s1;
            float s2 = g2[t] * rsqrtf(rv2[t] + 1e-5f);
            sc[512 + t] = s2;
            sc[768 + t] = b2[t] - rm2[t] * s2;
            zp[t] = 0u;            // 2KB zero page (512 u32)
            zp[t + 256] = 0u;
        }
    }
}

// ---- main: fused conv3x3 + BN (+skip) + ReLU via MFMA implicit GEMM --------
// m201-shaped: block = 64 c_out x ONE FULL IMAGE (32h x 32w), 8 waves (512
// thr), wave = 64co x (4h x 32w), acc[4][8] = 128 VGPR (m201's accumulator
// budget -- proven to fit 2 waves/SIMD without spill). grid = 256 = exactly
// 1 block/CU, one round, no tail.
// Why: all 64x256/acc[4][4] variants (R0-R6) sit at 81-87us because the MFMA
// pole (5.6K cyc/SIMD/step) ~equals the LDS-read pole (5.8K) and they don't
// overlap -> serial sum. This tile drops reads/MFMA 0.42 -> 0.25: per step
// MFMA 11.2K vs LDS 6.9K -- MFMA is the single dominant pole.
// LDS: A dbuf (2x36.9KB) + B single (73KB, whole image + halo) = 148.5KB.
// Staging role-split: waves 0-3 stage A (9 llds16, issued at step top into
// the other A-buf), waves 4-7 stage B (19 llds16, issued after the single
// mid-step barrier, shadowed by the 96-MFMA tail). Step-top vmcnt(0) drains
// only >=3.7K-cyc-old loads -> ~free. Per-image halo is self-contained.
__global__ __launch_bounds__(512, 2) void conv_mfma(
    const u16* __restrict__ Xt,    // NHWC bf16 input
    const u16* __restrict__ Wt,    // [9][256][256] bf16
    const float* __restrict__ sv,  // scale[256]
    const float* __restrict__ tv,  // shift[256]
    const float* __restrict__ skip,// NCHW f32 (stage2) or null
    u16* __restrict__ ybf,         // NHWC bf16 out (stage1)
    float* __restrict__ yf,        // NCHW f32 out (stage2)
    const u16* __restrict__ zp, int stage)
{
    __shared__ alignas(16) u16 ldsA[2][9 * 4 * 64 * 8];   // 2 x 36864 B
    __shared__ alignas(16) u16 ldsB[73 * 512];            // 74752 B (34x34x4 slots)

    int t = threadIdx.x;
    int wv = t >> 6, lane = t & 63;
    int q = lane >> 4, n16 = lane & 15;

    // decode: bid&7 = XCD slot; on one XCD the 4 co-tiles of the same image
    // run adjacent -> image X (512KB) is L2-resident for all 4.
    int bid = blockIdx.x;
    int co_t = (bid >> 3) & 3;
    int n = (bid & 7) | ((bid >> 5) << 3);     // image 0..63
    int co0 = co_t << 6;

    // ---- staging assignment (role-split by wave) ----
    // A-waves (0-3): 9 chunks each, g = wv*9+i -> (p=g>>2, mt=g&3);
    //   lane fetches Wt[p][co0 + mt*16 + n16][q*8 + kc].
    // B-waves (4-7): chunks g2 = (wv-4)+4j (73 total; wave4 gets 19, rest 18);
    //   slot s = g2*64+lane -> hi=s/136 (h=hi-1), wp=(s%136)>>2 (w=wp-1),
    //   qq=s&3; halo/OOB -> zero page (2KB: +kc stays in-bounds).
    bool isA = (wv < 4);
    u32 srcOff[19];                 // u16-element offsets (A: in Wt; B: in Xt)
    if (isA) {
#pragma unroll
        for (int i = 0; i < 9; ++i) {
            int g = wv * 9 + i;
            int p = g >> 2, mt = g & 3;
            srcOff[i] = (u32)((p << 16) + ((co0 + (mt << 4) + n16) << 8) + (q << 3));
        }
    } else {
        u32 zpOff = (u32)((const u16*)zp - Xt);
#pragma unroll
        for (int j = 0; j < 19; ++j) {
            int g2 = (wv - 4) + 4 * j;
            int s = g2 * 64 + lane;
            int hi = s / 136, rem = s - hi * 136;
            int wp = rem >> 2, qq = rem & 3;
            int h = hi - 1, w = wp - 1;
            bool v = (s < 4624) && (h >= 0) && (h < 32) && (w >= 0) && (w < 32);
            srcOff[j] = v ? (u32)(((n * 32 + h) * 32 + w) * 256 + (qq << 3))
                          : (zpOff + lane * 8);
        }
    }

    f32x4 acc[4][8] = {};

    // prologue: stage kc=0 (A -> buf0, B)
    if (isA) {
#pragma unroll
        for (int i = 0; i < 9; ++i)
            llds16((char*)&ldsA[0][0] + (((u32)(wv * 9 + i)) << 10), Xt ? (Wt + srcOff[i]) : 0);
    } else {
#pragma unroll
        for (int j = 0; j < 18; ++j)
            llds16((char*)ldsB + (((u32)((wv - 4) + 4 * j)) << 10), Xt + srcOff[j]);
        if (wv == 4)
            llds16((char*)ldsB + (72u << 10), Xt + srcOff[18]);
    }

    int c = 0;
    for (int kt = 0; kt < 8; ++kt) {
        // own loads are >=3.7K cyc old (issued last step top / mid) -> ~free;
        // barrier publishes all waves' staging.
        asm volatile("s_waitcnt vmcnt(0)" ::: "memory");
        __builtin_amdgcn_s_barrier();

        const u16* pA = ldsA[c];
        int kc1 = (kt + 1) << 5;
        // A-waves: issue A(kt+1) into the other buffer NOW (dbuf -> safe)
        if (kt < 7 && isA) {
#pragma unroll
            for (int i = 0; i < 9; ++i)
                llds16((char*)&ldsA[c ^ 1][0] + (((u32)(wv * 9 + i)) << 10),
                       Wt + srcOff[i] + kc1);
        }
        __builtin_amdgcn_sched_barrier(0);

        // ---- kw = 0,1: 12 B-frag reads, then per kh {4 A reads + 32 MFMA} ----
#pragma unroll
        for (int kw = 0; kw < 2; ++kw) {
            bf16x8 bFr[6][2];
#pragma unroll
            for (int rr = 0; rr < 6; ++rr)
#pragma unroll
                for (int half = 0; half < 2; ++half)
                    bFr[rr][half] = *(const bf16x8*)
                        &ldsB[(((wv * 4 + rr) * 34 + (half * 16 + n16 + kw)) * 4 + q) * 8];
            __builtin_amdgcn_s_setprio(1);
#pragma unroll
            for (int kh = 0; kh < 3; ++kh) {
                int p = kh * 3 + kw;
                bf16x8 aF[4];
#pragma unroll
                for (int mt = 0; mt < 4; ++mt)
                    aF[mt] = *(const bf16x8*)&pA[((p * 4 + mt) * 64 + lane) * 8];
#pragma unroll
                for (int mt = 0; mt < 4; ++mt)
#pragma unroll
                    for (int nt = 0; nt < 8; ++nt)
                        acc[mt][nt] = __builtin_amdgcn_mfma_f32_16x16x32_bf16(
                            aF[mt], bFr[(nt >> 1) + kh][nt & 1], acc[mt][nt], 0, 0, 0);
            }
            __builtin_amdgcn_s_setprio(0);
        }

        // ---- kw = 2: hoist the 12 B reads, mid barrier, B-stage, 96-MFMA tail
        bf16x8 bF2[6][2];
#pragma unroll
        for (int rr = 0; rr < 6; ++rr)
#pragma unroll
            for (int half = 0; half < 2; ++half)
                bF2[rr][half] = *(const bf16x8*)
                    &ldsB[(((wv * 4 + rr) * 34 + (half * 16 + n16 + 2)) * 4 + q) * 8];
        asm volatile("s_waitcnt lgkmcnt(0)" ::: "memory");
        __builtin_amdgcn_sched_barrier(0);
        __builtin_amdgcn_s_barrier();          // all B(kt) reads done block-wide

        if (kt < 7 && !isA) {                  // B-waves: issue B(kt+1)
#pragma unroll
            for (int j = 0; j < 18; ++j)
                llds16((char*)ldsB + (((u32)((wv - 4) + 4 * j)) << 10),
                       Xt + srcOff[j] + kc1);
            if (wv == 4)
                llds16((char*)ldsB + (72u << 10), Xt + srcOff[18] + kc1);
        }
        __builtin_amdgcn_sched_barrier(0);

        __builtin_amdgcn_s_setprio(1);
#pragma unroll
        for (int kh = 0; kh < 3; ++kh) {       // tail: A reads hit dbuf'd ldsA[c]
            int p = kh * 3 + 2;
            bf16x8 aF[4];
#pragma unroll
            for (int mt = 0; mt < 4; ++mt)
                aF[mt] = *(const bf16x8*)&pA[((p * 4 + mt) * 64 + lane) * 8];
#pragma unroll
            for (int mt = 0; mt < 4; ++mt)
#pragma unroll
                for (int nt = 0; nt < 8; ++nt)
                    acc[mt][nt] = __builtin_amdgcn_mfma_f32_16x16x32_bf16(
                        aF[mt], bF2[(nt >> 1) + kh][nt & 1], acc[mt][nt], 0, 0, 0);
        }
        __builtin_amdgcn_s_setprio(0);
        c ^= 1;
    }

    // epilogue: C/D layout col=lane&15 (spatial w), row=q*4+reg (c_out);
    // wave wv owns h rows wv*4 .. wv*4+3.
    if (stage == 1) {
#pragma unroll
        for (int mt = 0; mt < 4; ++mt) {
            int cb = co0 + (mt << 4) + (q << 2);
            f32x4 ss = *(const f32x4*)&sv[cb];
            f32x4 tt = *(const f32x4*)&tv[cb];
#pragma unroll
            for (int nt = 0; nt < 8; ++nt) {
                int h = (wv << 2) + (nt >> 1), w = ((nt & 1) << 4) + n16;
                ushort4 o;
                o.x = f2bf(fmaxf(acc[mt][nt][0] * ss[0] + tt[0], 0.f));
                o.y = f2bf(fmaxf(acc[mt][nt][1] * ss[1] + tt[1], 0.f));
                o.z = f2bf(fmaxf(acc[mt][nt][2] * ss[2] + tt[2], 0.f));
                o.w = f2bf(fmaxf(acc[mt][nt][3] * ss[3] + tt[3], 0.f));
                *(ushort4*)&ybf[((n * 32 + h) * 32 + w) * 256 + cb] = o;
            }
        }
    } else {
#pragma unroll
        for (int mt = 0; mt < 4; ++mt) {
            int cb = co0 + (mt << 4) + (q << 2);
            f32x4 ss = *(const f32x4*)&sv[cb];
            f32x4 tt = *(const f32x4*)&tv[cb];
#pragma unroll
            for (int nt = 0; nt < 8; ++nt) {
                int h = (wv << 2) + (nt >> 1), w = ((nt & 1) << 4) + n16;
#pragma unroll
                for (int j = 0; j < 4; ++j) {
                    int idx = (((n << 8) + cb + j) << 10) + (h << 5) + w;
                    yf[idx] = fmaxf(acc[mt][nt][j] * ss[j] + tt[j] + skip[idx], 0.f);
                }
            }
        }
    }
}

extern "C" void kernel_launch(void* const* d_in, const int* in_sizes, int n_in,
                              void* d_out, int out_size, void* d_ws, size_t ws_size,
                              hipStream_t stream) {
    const float* x   = (const float*)d_in[0];
    const float* w1  = (const float*)d_in[1];
    const float* g1  = (const float*)d_in[2];
    const float* b1  = (const float*)d_in[3];
    const float* rm1 = (const float*)d_in[4];
    const float* rv1 = (const float*)d_in[5];
    const float* w2  = (const float*)d_in[6];
    const float* g2  = (const float*)d_in[7];
    const float* b2  = (const float*)d_in[8];
    const float* rm2 = (const float*)d_in[9];
    const float* rv2 = (const float*)d_in[10];

    char* ws = (char*)d_ws;
    u16*  XT  = (u16*)(ws);                    // 32 MB NHWC bf16 x
    u16*  H1  = (u16*)(ws + 33554432);         // 32 MB NHWC bf16 intermediate
    u16*  W1t = (u16*)(ws + 67108864);         // 1.18 MB
    u16*  W2t = (u16*)(ws + 68288512);         // 1.18 MB
    float* sc = (float*)(ws + 69468160);       // s1|t1|s2|t2, 256 f32 each
    u32*  zpg = (u32*)(ws + 69472256);         // 2 KB zeros
    if (ws_size < 69474304) return;            // workspace too small — bail

    prep<<<16896, 256, 0, stream>>>(x, XT, w1, w2, W1t, W2t,
                                    g1, b1, rm1, rv1, g2, b2, rm2, rv2,
                                    sc, zpg);

    conv_mfma<<<256, 512, 0, stream>>>(XT, W1t, sc, sc + 256, nullptr,
                                       H1, nullptr, (const u16*)zpg, 1);
    conv_mfma<<<256, 512, 0, stream>>>(H1, W2t, sc + 512, sc + 768, x,
                                       nullptr, (float*)d_out, (const u16*)zpg, 2);
}